// Round 18
// baseline (502.795 us; speedup 1.0000x reference)
//
#include <hip/hip_runtime.h>
#include <hip/hip_bf16.h>
#include <math.h>

#define NB   512        // queries
#define ND   64         // dim
#define NC   1000000    // candidates
#define TOPK 100
#define SAMP 8192       // sampled candidates for threshold (rows 0..8191)
#define SAMP_R 8        // take 8th largest of sample as threshold
#define CAP  4096       // survivor buffer per query
#define MARGIN 0.5f     // bf16-scoring safety margin
#define NPAIR 15625     // NC / 64 (tile-pairs of 2x32 candidates)
#define K1GRID 512
#define QW   128        // per-wave queue capacity (window = 2 pairs, ~78 avg)
#define CPAD 16         // cnt stride: one 64B cache line per query

typedef __attribute__((ext_vector_type(8)))  short bf16x8;
typedef __attribute__((ext_vector_type(16))) float f32x16;

// f32 score, fma order d=0..63 IDENTICAL to the verified np-matching chain.
// c-side float4 loads, q-side scalar (LDS) — used by k0 and k2 fallback.
__device__ __forceinline__ float score_f32v(const float* __restrict__ c,
                                            const float* __restrict__ q)
{
    float s = 0.f;
    const float4* c4 = (const float4*)c;
#pragma unroll
    for (int i = 0; i < 16; ++i) {
        const float4 a = c4[i];
        s = fmaf(a.x, q[i * 4 + 0], s);
        s = fmaf(a.y, q[i * 4 + 1], s);
        s = fmaf(a.z, q[i * 4 + 2], s);
        s = fmaf(a.w, q[i * 4 + 3], s);
    }
    return s;
}

// Same chain, float4 on both sides (both 16B-aligned); bit-identical result.
__device__ __forceinline__ float score_f32q(const float* __restrict__ c,
                                            const float* __restrict__ q)
{
    float s = 0.f;
    const float4* c4 = (const float4*)c;
    const float4* q4 = (const float4*)q;
#pragma unroll
    for (int i = 0; i < 16; ++i) {
        const float4 a = c4[i], b = q4[i];
        s = fmaf(a.x, b.x, s);
        s = fmaf(a.y, b.y, s);
        s = fmaf(a.z, b.z, s);
        s = fmaf(a.w, b.w, s);
    }
    return s;
}

__device__ __forceinline__ unsigned int pack_bf16(float lo, float hi)
{
    unsigned int ul = __float_as_uint(lo), uh = __float_as_uint(hi);
    ul = (ul + 0x7fffu + ((ul >> 16) & 1u)) >> 16;   // RNE f32->bf16
    uh = (uh + 0x7fffu + ((uh >> 16) & 1u)) >> 16;
    return (uh << 16) | (ul & 0xffffu);
}

// HW packed f32->bf16 (prune path only; margin covers rounding-mode delta)
__device__ __forceinline__ unsigned int cvtpk(float lo, float hi)
{
    unsigned int r;
    asm("v_cvt_pk_bf16_f32 %0, %1, %2" : "=v"(r) : "v"(lo), "v"(hi));
    return r;
}

// Monotone f32 <-> uint mapping (order-preserving, handles negatives)
__device__ __forceinline__ unsigned fmap(float f)
{
    const unsigned u = __float_as_uint(f);
    return (u & 0x80000000u) ? ~u : (u | 0x80000000u);
}
__device__ __forceinline__ float funmap(unsigned m)
{
    return __uint_as_float((m & 0x80000000u) ? (m & 0x7fffffffu) : ~m);
}

// rank-th largest (1-based) of v[0..m). Exact (4x8-bit radix).
__device__ void radix_value_desc(const float* __restrict__ v, int m, int rank,
                                 int nthr, int tid,
                                 unsigned* hist, unsigned* cum, unsigned* bc,
                                 unsigned* out_mu, int* out_r, int* out_eq)
{
    unsigned pref = 0; int want = rank;
    for (int p = 24; p >= 0; p -= 8) {
        for (int b = tid; b < 256; b += nthr) hist[b] = 0;
        __syncthreads();
        for (int i = tid; i < m; i += nthr) {
            const unsigned mu = fmap(v[i]);
            if (p == 24 || ((mu >> (p + 8)) == (pref >> (p + 8))))
                atomicAdd(&hist[(mu >> p) & 255u], 1u);
        }
        __syncthreads();
        if (tid < 64) {   // suffix-scan cum[b] = sum_{b'>=b} hist[b']
            const unsigned h0 = hist[4*tid], h1 = hist[4*tid+1],
                           h2 = hist[4*tid+2], h3 = hist[4*tid+3];
            const unsigned g = h0 + h1 + h2 + h3;
            unsigned s = g;
#pragma unroll
            for (int off = 1; off < 64; off <<= 1) {
                const unsigned o = __shfl_down(s, off, 64);
                if (tid + off < 64) s += o;
            }
            const unsigned se = s - g;
            cum[4*tid+3] = h3 + se;
            cum[4*tid+2] = h2 + h3 + se;
            cum[4*tid+1] = h1 + h2 + h3 + se;
            cum[4*tid+0] = g + se;
        }
        __syncthreads();
        if (tid < 256) {
            const int c0 = (int)cum[tid];
            const int c1 = (tid == 255) ? 0 : (int)cum[tid + 1];
            if (c0 >= want && c1 < want) {
                bc[0] = pref | ((unsigned)tid << p);
                bc[1] = (unsigned)(want - c1);
                bc[2] = (unsigned)(c0 - c1);
            }
        }
        __syncthreads();
        pref = bc[0];
        want = (int)bc[1];
    }
    *out_mu = pref; *out_r = want; *out_eq = (int)bc[2];
}

// rank-th smallest (1-based) index among elements with fmap(v[i])==mustar.
__device__ int radix_index_asc(const float* __restrict__ v, const int* __restrict__ ix,
                               unsigned mustar, int m, int rank, int nthr, int tid,
                               unsigned* hist, unsigned* cum, unsigned* bc)
{
    unsigned pref = 0; int want = rank;
    for (int p = 16; p >= 0; p -= 8) {   // indices < 2^24
        for (int b = tid; b < 256; b += nthr) hist[b] = 0;
        __syncthreads();
        for (int i = tid; i < m; i += nthr) {
            if (fmap(v[i]) == mustar) {
                const unsigned k = (unsigned)ix[i];
                if (p == 16 || ((k >> (p + 8)) == (pref >> (p + 8))))
                    atomicAdd(&hist[(k >> p) & 255u], 1u);
            }
        }
        __syncthreads();
        if (tid < 64) {   // prefix-scan
            const unsigned h0 = hist[4*tid], h1 = hist[4*tid+1],
                           h2 = hist[4*tid+2], h3 = hist[4*tid+3];
            const unsigned g = h0 + h1 + h2 + h3;
            unsigned s = g;
#pragma unroll
            for (int off = 1; off < 64; off <<= 1) {
                const unsigned o = __shfl_up(s, off, 64);
                if ((int)tid - off >= 0) s += o;
            }
            const unsigned se = s - g;
            cum[4*tid+0] = se + h0;
            cum[4*tid+1] = se + h0 + h1;
            cum[4*tid+2] = se + h0 + h1 + h2;
            cum[4*tid+3] = se + g;
        }
        __syncthreads();
        if (tid < 256) {
            const int c0 = (int)cum[tid];
            const int cp = (tid == 0) ? 0 : (int)cum[tid - 1];
            if (c0 >= want && cp < want) {
                bc[0] = pref | ((unsigned)tid << p);
                bc[1] = (unsigned)(want - cp);
            }
        }
        __syncthreads();
        pref = bc[0];
        want = (int)bc[1];
    }
    return (int)pref;
}

// ---------------- KQ: Q f32 -> bf16 fragment-major + cnt zeroing -----------
__global__ __launch_bounds__(256) void kq_pack(const float* __restrict__ qs,
                                               unsigned int* __restrict__ qbf,
                                               unsigned int* __restrict__ cnt)
{
    const int g = blockIdx.x * 256 + threadIdx.x;   // 4096 chunks
    if (g >= 4096) return;
    cnt[g] = 0; cnt[g + 4096] = 0;                  // NB*CPAD = 8192 words
    const int qrow = g >> 3, c = g & 7;
    const float* src = qs + qrow * ND + c * 8;
    const float4 f0 = *(const float4*)src;
    const float4 f1 = *(const float4*)(src + 4);
    const int chunk = (((qrow >> 5) * 4 + (c >> 1)) * 64) + (c & 1) * 32 + (qrow & 31);
    uint4 w;
    w.x = pack_bf16(f0.x, f0.y); w.y = pack_bf16(f0.z, f0.w);
    w.z = pack_bf16(f1.x, f1.y); w.w = pack_bf16(f1.z, f1.w);
    *(uint4*)(qbf + (size_t)chunk * 4) = w;
}

// ---------------- K0: per-query threshold via radix select -----------------
__global__ __launch_bounds__(512) void k0_sample(const float* __restrict__ qs,
                                                 const float* __restrict__ cs,
                                                 float* __restrict__ T)
{
    __shared__ float ls[SAMP];          // 32 KB sample scores
    __shared__ float lq[ND];
    __shared__ unsigned hist[256], cum[256], bc[4];
    const int qi = blockIdx.x;
    const int tid = threadIdx.x;
    if (tid < ND) lq[tid] = qs[qi * ND + tid];
    __syncthreads();
    for (int j = tid; j < SAMP; j += 512)
        ls[j] = score_f32v(cs + (size_t)j * ND, lq);
    __syncthreads();
    unsigned mustar; int r, eq;
    radix_value_desc(ls, SAMP, SAMP_R, 512, tid, hist, cum, bc, &mustar, &r, &eq);
    if (tid == 0) T[qi] = funmap(mustar);
}

// ---------------- K1: barrier-free MFMA prune + DETECTION-time rescore -----
// Survivor rows are L1-hot at detection (their bytes were just consumed as
// A-fragments by this CU); qs rows are L2-pinned (128 KB, read by all blocks).
// Exact f32 score computed inline (bit-identical chain); queue and buf carry
// (query<<20|n, exact_bits) so k2 never touches cs.
__global__ __launch_bounds__(512, 4) void k1_mfma(const float* __restrict__ qs,
                                                  const unsigned int* __restrict__ qbf,
                                                  const float* __restrict__ cs,
                                                  const float* __restrict__ T,
                                                  unsigned int* __restrict__ cnt,
                                                  uint2* __restrict__ buf)
{
    __shared__ unsigned int qlds[16384];    // 64 KB: full Q, kq fragment layout
    __shared__ float tlds[NB];              // 2 KB: T - margin
    __shared__ uint2 qq[8][QW];             // 8 KB: per-wave queues
    __shared__ unsigned int qcnt[8];
    const int tid = threadIdx.x;
    const int wave = tid >> 6, lane = tid & 63;
    const int arow = lane & 31, khalf = lane >> 5;

    // one-time staging (the only block barrier in this kernel)
    for (int i = tid; i < 4096; i += 512)
        ((uint4*)qlds)[i] = ((const uint4*)qbf)[i];
    tlds[tid] = T[tid] - MARGIN;
    if (lane == 0) qcnt[wave] = 0;
    __syncthreads();

    const int stream = blockIdx.x * 8 + wave;
    int ip = 0;

    for (int p = stream; p < NPAIR; p += K1GRID * 8) {
        const int t0 = p * 2, t1 = t0 + 1;

        // A-fragments for both 32-row tiles, direct from global (coalesced)
        bf16x8 af0[4], af1[4];
#pragma unroll
        for (int k0 = 0; k0 < 4; ++k0) {
            const float* p0 = cs + (size_t)(t0 * 32 + arow) * ND + k0 * 16 + khalf * 8;
            const float* p1 = cs + (size_t)(t1 * 32 + arow) * ND + k0 * 16 + khalf * 8;
            const float4 a0 = *(const float4*)p0, a1 = *(const float4*)(p0 + 4);
            const float4 b0 = *(const float4*)p1, b1 = *(const float4*)(p1 + 4);
            union { unsigned int u[4]; bf16x8 v; } u0, u1;
            u0.u[0] = cvtpk(a0.x, a0.y); u0.u[1] = cvtpk(a0.z, a0.w);
            u0.u[2] = cvtpk(a1.x, a1.y); u0.u[3] = cvtpk(a1.z, a1.w);
            u1.u[0] = cvtpk(b0.x, b0.y); u1.u[1] = cvtpk(b0.z, b0.w);
            u1.u[2] = cvtpk(b1.x, b1.y); u1.u[3] = cvtpk(b1.z, b1.w);
            af0[k0] = u0.v; af1[k0] = u1.v;
        }

        for (int qt = 0; qt < 16; ++qt) {
            f32x16 acc0, acc1;
#pragma unroll
            for (int i = 0; i < 16; ++i) { acc0[i] = 0.f; acc1[i] = 0.f; }
#pragma unroll
            for (int k0 = 0; k0 < 4; ++k0) {
                union { uint4 q; bf16x8 v; } u;
                u.q = *(const uint4*)(qlds + ((size_t)(qt * 4 + k0) * 64 + lane) * 4);
                acc0 = __builtin_amdgcn_mfma_f32_32x32x16_bf16(af0[k0], u.v, acc0, 0, 0, 0);
                acc1 = __builtin_amdgcn_mfma_f32_32x32x16_bf16(af1[k0], u.v, acc1, 0, 0, 0);
            }
            const int query = qt * 32 + arow;
            const float tm = tlds[query];
            // combined survivor mask: bits 0-15 tile t0, bits 16-31 tile t1
            unsigned mm = 0u;
#pragma unroll
            for (int r = 0; r < 16; ++r) {
                mm |= (acc0[r] >= tm) ? (1u << r) : 0u;
                mm |= (acc1[r] >= tm) ? (1u << (r + 16)) : 0u;
            }
            while (mm) {
                const int r = __builtin_ctz(mm); mm &= mm - 1u;
                const int rr = r & 15;
                const int n = (t0 + (r >> 4)) * 32 + (rr & 3) + 8 * (rr >> 2) + 4 * khalf;
                // exact rescore NOW: cs row L1-hot (just consumed as A-frags),
                // qs row L2-pinned. Bit-identical f32 chain.
                const float s = score_f32q(cs + (size_t)n * ND, qs + (size_t)query * ND);
                const unsigned qp = atomicAdd(&qcnt[wave], 1u);
                if (qp < QW)
                    qq[wave][qp] = make_uint2(((unsigned)query << 20) | (unsigned)n,
                                              __float_as_uint(s));
                else { const unsigned pp = atomicAdd(&cnt[query * CPAD], 1u);
                       if (pp < CAP) buf[(size_t)query * CAP + pp] =
                           make_uint2((unsigned)n, __float_as_uint(s)); }
            }
        }

        // drain every 2nd pair (and on this wave's last pair): pure copy
        const bool last = (p + K1GRID * 8 >= NPAIR);
        if (ip || last) {
            asm volatile("s_waitcnt lgkmcnt(0)" ::: "memory");   // pushes visible
            __builtin_amdgcn_sched_barrier(0);
            unsigned qn = 0;
            if (lane == 0) qn = atomicExch(&qcnt[wave], 0u);     // read + reset
            qn = __shfl(qn, 0);
            const unsigned qlim = qn < QW ? qn : QW;
            for (unsigned i = lane; i < qlim; i += 64) {
                const uint2 e = qq[wave][i];
                const unsigned q = e.x >> 20, n = e.x & 0xFFFFFu;
                const unsigned pp = atomicAdd(&cnt[q * CPAD], 1u);
                if (pp < CAP) buf[(size_t)q * CAP + pp] = make_uint2(n, e.y);
            }
            asm volatile("s_waitcnt lgkmcnt(0)" ::: "memory");   // reset visible
            __builtin_amdgcn_sched_barrier(0);
            ip = 0;
        } else ip = 1;
    }
}

// ---------------- K2: select top-K from stored (n, score) pairs ------------
__device__ __forceinline__ bool prec(float av, int ai, float bv, int bi)
{
    return (av > bv) || (av == bv && ai < bi);
}

__device__ void bitonic_desc(float* v, int* ix, int n, int tid, int nthr)
{
    for (int k = 2; k <= n; k <<= 1) {
        for (int j = k >> 1; j > 0; j >>= 1) {
            for (int i = tid; i < n; i += nthr) {
                int p = i ^ j;
                if (p > i) {
                    bool swap_;
                    if ((i & k) == 0) swap_ = prec(v[p], ix[p], v[i], ix[i]);
                    else              swap_ = prec(v[i], ix[i], v[p], ix[p]);
                    if (swap_) {
                        float tv_ = v[i]; v[i] = v[p]; v[p] = tv_;
                        int   ti_ = ix[i]; ix[i] = ix[p]; ix[p] = ti_;
                    }
                }
            }
            __syncthreads();
        }
    }
}

__global__ __launch_bounds__(1024) void k2_final(const float* __restrict__ qs,
                                                 const float* __restrict__ cs,
                                                 const unsigned int* __restrict__ cnt,
                                                 const uint2* __restrict__ buf,
                                                 float* __restrict__ out)
{
    __shared__ float sv[CAP];
    __shared__ int   si[CAP];
    __shared__ float lq[ND];
    __shared__ unsigned hist[256], cum[256], bc[4];
    __shared__ float fv[128];
    __shared__ int   fi[128];
    __shared__ float tv[128];
    __shared__ int   ti[128];
    const int qi = blockIdx.x;
    const int tid = threadIdx.x;
    if (tid < ND) lq[tid] = qs[qi * ND + tid];
    __syncthreads();
    const unsigned int c = cnt[qi * CPAD];
    const bool fix = (c < TOPK) || (c > CAP);
    if (!fix) {
        const int m = (int)c;
        for (int i = tid; i < m; i += 1024) {       // coalesced 8B loads, no cs!
            const uint2 e = buf[(size_t)qi * CAP + i];
            sv[i] = __uint_as_float(e.y);
            si[i] = (int)e.x;
        }
        __syncthreads();
        unsigned mustar; int r, eq;
        radix_value_desc(sv, m, TOPK, 1024, tid, hist, cum, bc, &mustar, &r, &eq);
        int idxstar = 0x7fffffff;
        if (r < eq)
            idxstar = radix_index_asc(sv, si, mustar, m, r, 1024, tid, hist, cum, bc);
        if (tid == 0) bc[3] = 0;
        __syncthreads();
        for (int i = tid; i < m; i += 1024) {
            const unsigned mu = fmap(sv[i]);
            if (mu > mustar || (mu == mustar && si[i] <= idxstar)) {
                const unsigned p = atomicAdd(&bc[3], 1u);
                if (p < 128) { fv[p] = sv[i]; fi[p] = si[i]; }
            }
        }
        __syncthreads();
        for (int i = tid; i < 128; i += 1024)
            if (i >= TOPK) { fv[i] = -INFINITY; fi[i] = 0x7fffffff; }
        __syncthreads();
        bitonic_desc(fv, fi, 128, tid, 1024);
        for (int j = tid; j < TOPK; j += 1024) {
            out[qi * TOPK + j] = fv[j];
            out[NB * TOPK + qi * TOPK + j] = (float)fi[j];
        }
    } else {
        // exact fallback (rare): chunked full scan with carried top-128
        for (int i = tid; i < 128; i += 1024) { tv[i] = -INFINITY; ti[i] = 0x7fffffff; }
        __syncthreads();
        const int CH = CAP - 128;
        for (int base = 0; base < NC; base += CH) {
            for (int i = tid; i < CAP; i += 1024) {
                if (i < 128) { sv[i] = tv[i]; si[i] = ti[i]; }
                else {
                    const int n = base + (i - 128);
                    if (n < NC) {
                        sv[i] = score_f32v(cs + (size_t)n * ND, lq);
                        si[i] = n;
                    } else { sv[i] = -INFINITY; si[i] = 0x7fffffff; }
                }
            }
            __syncthreads();
            bitonic_desc(sv, si, CAP, tid, 1024);
            for (int i = tid; i < 128; i += 1024) { tv[i] = sv[i]; ti[i] = si[i]; }
            __syncthreads();
        }
        for (int j = tid; j < TOPK; j += 1024) {
            out[qi * TOPK + j] = tv[j];
            out[NB * TOPK + qi * TOPK + j] = (float)ti[j];
        }
    }
}

extern "C" void kernel_launch(void* const* d_in, const int* in_sizes, int n_in,
                              void* d_out, int out_size, void* d_ws, size_t ws_size,
                              hipStream_t stream)
{
    const float* qs = (const float*)d_in[0];
    const float* cs = (const float*)d_in[1];
    float*        T   = (float*)d_ws;                                   // 2 KB
    unsigned int* cnt = (unsigned int*)((char*)d_ws + 4096);            // 32 KB
    unsigned int* qbf = (unsigned int*)((char*)d_ws + 4096 + 32768);    // 64 KB
    uint2*        buf = (uint2*)((char*)d_ws + 4096 + 32768 + 65536);   // 16 MB
    float* out = (float*)d_out;

    kq_pack<<<16, 256, 0, stream>>>(qs, qbf, cnt);
    k0_sample<<<NB, 512, 0, stream>>>(qs, cs, T);
    k1_mfma<<<K1GRID, 512, 0, stream>>>(qs, qbf, cs, T, cnt, buf);
    k2_final<<<NB, 1024, 0, stream>>>(qs, cs, cnt, buf, out);
}

// Round 19
// 280.423 us; speedup vs baseline: 1.7930x; 1.7930x over previous
//
#include <hip/hip_runtime.h>
#include <hip/hip_bf16.h>
#include <math.h>

#define NB   512        // queries
#define ND   64         // dim
#define NC   1000000    // candidates
#define TOPK 100
#define SAMP 8192       // sampled candidates for threshold (rows 0..8191)
#define SAMP_R 8        // take 8th largest of sample as threshold
#define CAP  4096       // survivor buffer per query
#define MARGIN 0.5f     // bf16-scoring safety margin (|approx-exact| bound)
#define BAND 1.0f       // band below 100th approx: 2*MARGIN
#define BANDCAP 1024    // max band size for exact rescore
#define NPAIR 15625     // NC / 64 (tile-pairs of 2x32 candidates)
#define K1GRID 512
#define QW   128        // per-wave queue capacity (window = 2 pairs, ~78 avg)
#define CPAD 16         // cnt stride: one 64B cache line per query

typedef __attribute__((ext_vector_type(8)))  short bf16x8;
typedef __attribute__((ext_vector_type(16))) float f32x16;

// f32 score, fma order d=0..63 IDENTICAL to the verified np-matching chain.
__device__ __forceinline__ float score_f32v(const float* __restrict__ c,
                                            const float* __restrict__ q)
{
    float s = 0.f;
    const float4* c4 = (const float4*)c;
#pragma unroll
    for (int i = 0; i < 16; ++i) {
        const float4 a = c4[i];
        s = fmaf(a.x, q[i * 4 + 0], s);
        s = fmaf(a.y, q[i * 4 + 1], s);
        s = fmaf(a.z, q[i * 4 + 2], s);
        s = fmaf(a.w, q[i * 4 + 3], s);
    }
    return s;
}

__device__ __forceinline__ unsigned int pack_bf16(float lo, float hi)
{
    unsigned int ul = __float_as_uint(lo), uh = __float_as_uint(hi);
    ul = (ul + 0x7fffu + ((ul >> 16) & 1u)) >> 16;   // RNE f32->bf16
    uh = (uh + 0x7fffu + ((uh >> 16) & 1u)) >> 16;
    return (uh << 16) | (ul & 0xffffu);
}

// HW packed f32->bf16 (prune path only; margin covers rounding-mode delta)
__device__ __forceinline__ unsigned int cvtpk(float lo, float hi)
{
    unsigned int r;
    asm("v_cvt_pk_bf16_f32 %0, %1, %2" : "=v"(r) : "v"(lo), "v"(hi));
    return r;
}

// Monotone f32 <-> uint mapping (order-preserving, handles negatives)
__device__ __forceinline__ unsigned fmap(float f)
{
    const unsigned u = __float_as_uint(f);
    return (u & 0x80000000u) ? ~u : (u | 0x80000000u);
}
__device__ __forceinline__ float funmap(unsigned m)
{
    return __uint_as_float((m & 0x80000000u) ? (m & 0x7fffffffu) : ~m);
}

// rank-th largest (1-based) of v[0..m). Exact (4x8-bit radix).
__device__ void radix_value_desc(const float* __restrict__ v, int m, int rank,
                                 int nthr, int tid,
                                 unsigned* hist, unsigned* cum, unsigned* bc,
                                 unsigned* out_mu, int* out_r, int* out_eq)
{
    unsigned pref = 0; int want = rank;
    for (int p = 24; p >= 0; p -= 8) {
        for (int b = tid; b < 256; b += nthr) hist[b] = 0;
        __syncthreads();
        for (int i = tid; i < m; i += nthr) {
            const unsigned mu = fmap(v[i]);
            if (p == 24 || ((mu >> (p + 8)) == (pref >> (p + 8))))
                atomicAdd(&hist[(mu >> p) & 255u], 1u);
        }
        __syncthreads();
        if (tid < 64) {   // suffix-scan cum[b] = sum_{b'>=b} hist[b']
            const unsigned h0 = hist[4*tid], h1 = hist[4*tid+1],
                           h2 = hist[4*tid+2], h3 = hist[4*tid+3];
            const unsigned g = h0 + h1 + h2 + h3;
            unsigned s = g;
#pragma unroll
            for (int off = 1; off < 64; off <<= 1) {
                const unsigned o = __shfl_down(s, off, 64);
                if (tid + off < 64) s += o;
            }
            const unsigned se = s - g;
            cum[4*tid+3] = h3 + se;
            cum[4*tid+2] = h2 + h3 + se;
            cum[4*tid+1] = h1 + h2 + h3 + se;
            cum[4*tid+0] = g + se;
        }
        __syncthreads();
        if (tid < 256) {
            const int c0 = (int)cum[tid];
            const int c1 = (tid == 255) ? 0 : (int)cum[tid + 1];
            if (c0 >= want && c1 < want) {
                bc[0] = pref | ((unsigned)tid << p);
                bc[1] = (unsigned)(want - c1);
                bc[2] = (unsigned)(c0 - c1);
            }
        }
        __syncthreads();
        pref = bc[0];
        want = (int)bc[1];
    }
    *out_mu = pref; *out_r = want; *out_eq = (int)bc[2];
}

// rank-th smallest (1-based) index among elements with fmap(v[i])==mustar.
__device__ int radix_index_asc(const float* __restrict__ v, const int* __restrict__ ix,
                               unsigned mustar, int m, int rank, int nthr, int tid,
                               unsigned* hist, unsigned* cum, unsigned* bc)
{
    unsigned pref = 0; int want = rank;
    for (int p = 16; p >= 0; p -= 8) {   // indices < 2^24
        for (int b = tid; b < 256; b += nthr) hist[b] = 0;
        __syncthreads();
        for (int i = tid; i < m; i += nthr) {
            if (fmap(v[i]) == mustar) {
                const unsigned k = (unsigned)ix[i];
                if (p == 16 || ((k >> (p + 8)) == (pref >> (p + 8))))
                    atomicAdd(&hist[(k >> p) & 255u], 1u);
            }
        }
        __syncthreads();
        if (tid < 64) {   // prefix-scan
            const unsigned h0 = hist[4*tid], h1 = hist[4*tid+1],
                           h2 = hist[4*tid+2], h3 = hist[4*tid+3];
            const unsigned g = h0 + h1 + h2 + h3;
            unsigned s = g;
#pragma unroll
            for (int off = 1; off < 64; off <<= 1) {
                const unsigned o = __shfl_up(s, off, 64);
                if ((int)tid - off >= 0) s += o;
            }
            const unsigned se = s - g;
            cum[4*tid+0] = se + h0;
            cum[4*tid+1] = se + h0 + h1;
            cum[4*tid+2] = se + h0 + h1 + h2;
            cum[4*tid+3] = se + g;
        }
        __syncthreads();
        if (tid < 256) {
            const int c0 = (int)cum[tid];
            const int cp = (tid == 0) ? 0 : (int)cum[tid - 1];
            if (c0 >= want && cp < want) {
                bc[0] = pref | ((unsigned)tid << p);
                bc[1] = (unsigned)(want - cp);
            }
        }
        __syncthreads();
        pref = bc[0];
        want = (int)bc[1];
    }
    return (int)pref;
}

// ---------------- KQ: Q f32 -> bf16 fragment-major + cnt zeroing -----------
__global__ __launch_bounds__(256) void kq_pack(const float* __restrict__ qs,
                                               unsigned int* __restrict__ qbf,
                                               unsigned int* __restrict__ cnt)
{
    const int g = blockIdx.x * 256 + threadIdx.x;   // 4096 chunks
    if (g >= 4096) return;
    cnt[g] = 0; cnt[g + 4096] = 0;                  // NB*CPAD = 8192 words
    const int qrow = g >> 3, c = g & 7;
    const float* src = qs + qrow * ND + c * 8;
    const float4 f0 = *(const float4*)src;
    const float4 f1 = *(const float4*)(src + 4);
    const int chunk = (((qrow >> 5) * 4 + (c >> 1)) * 64) + (c & 1) * 32 + (qrow & 31);
    uint4 w;
    w.x = pack_bf16(f0.x, f0.y); w.y = pack_bf16(f0.z, f0.w);
    w.z = pack_bf16(f1.x, f1.y); w.w = pack_bf16(f1.z, f1.w);
    *(uint4*)(qbf + (size_t)chunk * 4) = w;
}

// ---------------- K0: per-query threshold via radix select -----------------
__global__ __launch_bounds__(512) void k0_sample(const float* __restrict__ qs,
                                                 const float* __restrict__ cs,
                                                 float* __restrict__ T)
{
    __shared__ float ls[SAMP];          // 32 KB sample scores
    __shared__ float lq[ND];
    __shared__ unsigned hist[256], cum[256], bc[4];
    const int qi = blockIdx.x;
    const int tid = threadIdx.x;
    if (tid < ND) lq[tid] = qs[qi * ND + tid];
    __syncthreads();
    for (int j = tid; j < SAMP; j += 512)
        ls[j] = score_f32v(cs + (size_t)j * ND, lq);
    __syncthreads();
    unsigned mustar; int r, eq;
    radix_value_desc(ls, SAMP, SAMP_R, 512, tid, hist, cum, bc, &mustar, &r, &eq);
    if (tid == 0) T[qi] = funmap(mustar);
}

// ---------------- K1: barrier-free MFMA prune, stores APPROX score ---------
// r16 structure (prune-only, fast). The approx (MFMA) score is free in the
// accumulator; extract via cndmask tree on the rare pop path and store it so
// k2 can band-select before its exact gather.
__global__ __launch_bounds__(512, 4) void k1_mfma(const unsigned int* __restrict__ qbf,
                                                  const float* __restrict__ cs,
                                                  const float* __restrict__ T,
                                                  unsigned int* __restrict__ cnt,
                                                  uint2* __restrict__ buf)
{
    __shared__ unsigned int qlds[16384];    // 64 KB: full Q, kq fragment layout
    __shared__ float tlds[NB];              // 2 KB: T - margin
    __shared__ uint2 qq[8][QW];             // 8 KB: per-wave queues
    __shared__ unsigned int qcnt[8];
    const int tid = threadIdx.x;
    const int wave = tid >> 6, lane = tid & 63;
    const int arow = lane & 31, khalf = lane >> 5;

    // one-time staging (the only block barrier in this kernel)
    for (int i = tid; i < 4096; i += 512)
        ((uint4*)qlds)[i] = ((const uint4*)qbf)[i];
    tlds[tid] = T[tid] - MARGIN;
    if (lane == 0) qcnt[wave] = 0;
    __syncthreads();

    const int stream = blockIdx.x * 8 + wave;
    int ip = 0;

    for (int p = stream; p < NPAIR; p += K1GRID * 8) {
        const int t0 = p * 2, t1 = t0 + 1;

        // A-fragments for both 32-row tiles, direct from global (coalesced)
        bf16x8 af0[4], af1[4];
#pragma unroll
        for (int k0 = 0; k0 < 4; ++k0) {
            const float* p0 = cs + (size_t)(t0 * 32 + arow) * ND + k0 * 16 + khalf * 8;
            const float* p1 = cs + (size_t)(t1 * 32 + arow) * ND + k0 * 16 + khalf * 8;
            const float4 a0 = *(const float4*)p0, a1 = *(const float4*)(p0 + 4);
            const float4 b0 = *(const float4*)p1, b1 = *(const float4*)(p1 + 4);
            union { unsigned int u[4]; bf16x8 v; } u0, u1;
            u0.u[0] = cvtpk(a0.x, a0.y); u0.u[1] = cvtpk(a0.z, a0.w);
            u0.u[2] = cvtpk(a1.x, a1.y); u0.u[3] = cvtpk(a1.z, a1.w);
            u1.u[0] = cvtpk(b0.x, b0.y); u1.u[1] = cvtpk(b0.z, b0.w);
            u1.u[2] = cvtpk(b1.x, b1.y); u1.u[3] = cvtpk(b1.z, b1.w);
            af0[k0] = u0.v; af1[k0] = u1.v;
        }

        for (int qt = 0; qt < 16; ++qt) {
            f32x16 acc0, acc1;
#pragma unroll
            for (int i = 0; i < 16; ++i) { acc0[i] = 0.f; acc1[i] = 0.f; }
#pragma unroll
            for (int k0 = 0; k0 < 4; ++k0) {
                union { uint4 q; bf16x8 v; } u;
                u.q = *(const uint4*)(qlds + ((size_t)(qt * 4 + k0) * 64 + lane) * 4);
                acc0 = __builtin_amdgcn_mfma_f32_32x32x16_bf16(af0[k0], u.v, acc0, 0, 0, 0);
                acc1 = __builtin_amdgcn_mfma_f32_32x32x16_bf16(af1[k0], u.v, acc1, 0, 0, 0);
            }
            const int query = qt * 32 + arow;
            const float tm = tlds[query];
            // combined survivor mask: bits 0-15 tile t0, bits 16-31 tile t1
            unsigned mm = 0u;
#pragma unroll
            for (int r = 0; r < 16; ++r) {
                mm |= (acc0[r] >= tm) ? (1u << r) : 0u;
                mm |= (acc1[r] >= tm) ? (1u << (r + 16)) : 0u;
            }
            while (mm) {
                const int r = __builtin_ctz(mm); mm &= mm - 1u;
                const int rr = r & 15;
                // extract acc[rr] without scratch (static-index select tree)
                float s0 = 0.f, s1 = 0.f;
#pragma unroll
                for (int k = 0; k < 16; ++k) {
                    s0 = (rr == k) ? acc0[k] : s0;
                    s1 = (rr == k) ? acc1[k] : s1;
                }
                const float sc = (r & 16) ? s1 : s0;
                const int n = (t0 + (r >> 4)) * 32 + (rr & 3) + 8 * (rr >> 2) + 4 * khalf;
                const unsigned qp = atomicAdd(&qcnt[wave], 1u);
                if (qp < QW)
                    qq[wave][qp] = make_uint2(((unsigned)query << 20) | (unsigned)n,
                                              __float_as_uint(sc));
                else { const unsigned pp = atomicAdd(&cnt[query * CPAD], 1u);
                       if (pp < CAP) buf[(size_t)query * CAP + pp] =
                           make_uint2((unsigned)n, __float_as_uint(sc)); }
            }
        }

        // drain every 2nd pair (and on this wave's last pair): pure copy
        const bool last = (p + K1GRID * 8 >= NPAIR);
        if (ip || last) {
            asm volatile("s_waitcnt lgkmcnt(0)" ::: "memory");   // pushes visible
            __builtin_amdgcn_sched_barrier(0);
            unsigned qn = 0;
            if (lane == 0) qn = atomicExch(&qcnt[wave], 0u);     // read + reset
            qn = __shfl(qn, 0);
            const unsigned qlim = qn < QW ? qn : QW;
            for (unsigned i = lane; i < qlim; i += 64) {
                const uint2 e = qq[wave][i];
                const unsigned q = e.x >> 20, n = e.x & 0xFFFFFu;
                const unsigned pp = atomicAdd(&cnt[q * CPAD], 1u);
                if (pp < CAP) buf[(size_t)q * CAP + pp] = make_uint2(n, e.y);
            }
            asm volatile("s_waitcnt lgkmcnt(0)" ::: "memory");   // reset visible
            __builtin_amdgcn_sched_barrier(0);
            ip = 0;
        } else ip = 1;
    }
}

// ---------------- K2: approx band-select -> exact rescore of band ----------
__device__ __forceinline__ bool prec(float av, int ai, float bv, int bi)
{
    return (av > bv) || (av == bv && ai < bi);
}

__device__ void bitonic_desc(float* v, int* ix, int n, int tid, int nthr)
{
    for (int k = 2; k <= n; k <<= 1) {
        for (int j = k >> 1; j > 0; j >>= 1) {
            for (int i = tid; i < n; i += nthr) {
                int p = i ^ j;
                if (p > i) {
                    bool swap_;
                    if ((i & k) == 0) swap_ = prec(v[p], ix[p], v[i], ix[i]);
                    else              swap_ = prec(v[i], ix[i], v[p], ix[p]);
                    if (swap_) {
                        float tv_ = v[i]; v[i] = v[p]; v[p] = tv_;
                        int   ti_ = ix[i]; ix[i] = ix[p]; ix[p] = ti_;
                    }
                }
            }
            __syncthreads();
        }
    }
}

__global__ __launch_bounds__(1024) void k2_final(const float* __restrict__ qs,
                                                 const float* __restrict__ cs,
                                                 const unsigned int* __restrict__ cnt,
                                                 const uint2* __restrict__ buf,
                                                 float* __restrict__ out)
{
    __shared__ float sv[CAP];          // approx, then reused for exact band
    __shared__ int   si[CAP];          // survivor n
    __shared__ int   bi[BANDCAP];      // band indices
    __shared__ float lq[ND];
    __shared__ unsigned hist[256], cum[256], bc[4];
    __shared__ float fv[128];
    __shared__ int   fi[128];
    __shared__ float tv[128];
    __shared__ int   ti[128];
    const int qi = blockIdx.x;
    const int tid = threadIdx.x;
    if (tid < ND) lq[tid] = qs[qi * ND + tid];
    __syncthreads();
    const unsigned int c = cnt[qi * CPAD];
    const bool fix = (c < TOPK) || (c > CAP);
    if (!fix) {
        const int m = (int)c;
        for (int i = tid; i < m; i += 1024) {       // coalesced 8B loads
            const uint2 e = buf[(size_t)qi * CAP + i];
            sv[i] = __uint_as_float(e.y);           // approx score
            si[i] = (int)e.x;                       // candidate index
        }
        __syncthreads();
        // 100th-largest APPROX score
        unsigned mustar_a; int ra, eqa;
        radix_value_desc(sv, m, TOPK, 1024, tid, hist, cum, bc, &mustar_a, &ra, &eqa);
        const float ca = funmap(mustar_a) - BAND;   // band cutoff
        if (tid == 0) bc[3] = 0;
        __syncthreads();
        for (int i = tid; i < m; i += 1024) {       // compact band
            if (sv[i] >= ca) {
                const unsigned p = atomicAdd(&bc[3], 1u);
                if (p < BANDCAP) bi[p] = si[i];
            }
        }
        __syncthreads();
        const int mb = (int)bc[3];
        if (mb <= BANDCAP) {
            // exact rescore of band only (~150-200 rows)
            for (int j = tid; j < mb; j += 1024)
                sv[j] = score_f32v(cs + (size_t)bi[j] * ND, lq);
            __syncthreads();
            unsigned mustar; int r, eq;
            radix_value_desc(sv, mb, TOPK, 1024, tid, hist, cum, bc, &mustar, &r, &eq);
            int idxstar = 0x7fffffff;
            if (r < eq)
                idxstar = radix_index_asc(sv, bi, mustar, mb, r, 1024, tid, hist, cum, bc);
            if (tid == 0) bc[3] = 0;
            __syncthreads();
            for (int i = tid; i < mb; i += 1024) {
                const unsigned mu = fmap(sv[i]);
                if (mu > mustar || (mu == mustar && bi[i] <= idxstar)) {
                    const unsigned p = atomicAdd(&bc[3], 1u);
                    if (p < 128) { fv[p] = sv[i]; fi[p] = bi[i]; }
                }
            }
        } else {
            // band overflow (~never): exact rescore of ALL survivors
            __syncthreads();
            for (int i = tid; i < m; i += 1024)
                sv[i] = score_f32v(cs + (size_t)si[i] * ND, lq);
            __syncthreads();
            unsigned mustar; int r, eq;
            radix_value_desc(sv, m, TOPK, 1024, tid, hist, cum, bc, &mustar, &r, &eq);
            int idxstar = 0x7fffffff;
            if (r < eq)
                idxstar = radix_index_asc(sv, si, mustar, m, r, 1024, tid, hist, cum, bc);
            if (tid == 0) bc[3] = 0;
            __syncthreads();
            for (int i = tid; i < m; i += 1024) {
                const unsigned mu = fmap(sv[i]);
                if (mu > mustar || (mu == mustar && si[i] <= idxstar)) {
                    const unsigned p = atomicAdd(&bc[3], 1u);
                    if (p < 128) { fv[p] = sv[i]; fi[p] = si[i]; }
                }
            }
        }
        __syncthreads();
        for (int i = tid; i < 128; i += 1024)
            if (i >= TOPK) { fv[i] = -INFINITY; fi[i] = 0x7fffffff; }
        __syncthreads();
        bitonic_desc(fv, fi, 128, tid, 1024);
        for (int j = tid; j < TOPK; j += 1024) {
            out[qi * TOPK + j] = fv[j];
            out[NB * TOPK + qi * TOPK + j] = (float)fi[j];
        }
    } else {
        // exact fallback (rare): chunked full scan with carried top-128
        for (int i = tid; i < 128; i += 1024) { tv[i] = -INFINITY; ti[i] = 0x7fffffff; }
        __syncthreads();
        const int CH = CAP - 128;
        for (int base = 0; base < NC; base += CH) {
            for (int i = tid; i < CAP; i += 1024) {
                if (i < 128) { sv[i] = tv[i]; si[i] = ti[i]; }
                else {
                    const int n = base + (i - 128);
                    if (n < NC) {
                        sv[i] = score_f32v(cs + (size_t)n * ND, lq);
                        si[i] = n;
                    } else { sv[i] = -INFINITY; si[i] = 0x7fffffff; }
                }
            }
            __syncthreads();
            bitonic_desc(sv, si, CAP, tid, 1024);
            for (int i = tid; i < 128; i += 1024) { tv[i] = sv[i]; ti[i] = si[i]; }
            __syncthreads();
        }
        for (int j = tid; j < TOPK; j += 1024) {
            out[qi * TOPK + j] = tv[j];
            out[NB * TOPK + qi * TOPK + j] = (float)ti[j];
        }
    }
}

extern "C" void kernel_launch(void* const* d_in, const int* in_sizes, int n_in,
                              void* d_out, int out_size, void* d_ws, size_t ws_size,
                              hipStream_t stream)
{
    const float* qs = (const float*)d_in[0];
    const float* cs = (const float*)d_in[1];
    float*        T   = (float*)d_ws;                                   // 2 KB
    unsigned int* cnt = (unsigned int*)((char*)d_ws + 4096);            // 32 KB
    unsigned int* qbf = (unsigned int*)((char*)d_ws + 4096 + 32768);    // 64 KB
    uint2*        buf = (uint2*)((char*)d_ws + 4096 + 32768 + 65536);   // 16 MB
    float* out = (float*)d_out;

    kq_pack<<<16, 256, 0, stream>>>(qs, qbf, cnt);
    k0_sample<<<NB, 512, 0, stream>>>(qs, cs, T);
    k1_mfma<<<K1GRID, 512, 0, stream>>>(qbf, cs, T, cnt, buf);
    k2_final<<<NB, 1024, 0, stream>>>(qs, cs, cnt, buf, out);
}